// Round 2
// baseline (410.146 us; speedup 1.0000x reference)
//
#include <hip/hip_runtime.h>

#define NN 4096
#define NE 65536
#define ND 64

// ---------------- K1: per-node dot products (srel, sroot only) ----------------
__global__ void k1_node_dots(const float* __restrict__ x, const float* __restrict__ wrel,
                             const float* __restrict__ wroot, double* __restrict__ srel,
                             double* __restrict__ sroot) {
    int gt = blockIdx.x * blockDim.x + threadIdx.x;
    int node = gt >> 6, lane = gt & 63;
    if (node >= NN) return;
    double xv = (double)x[node * ND + lane];
    double pr = xv * (double)wrel[lane];
    double po = xv * (double)wroot[lane];
    for (int off = 32; off > 0; off >>= 1) {
        pr += __shfl_down(pr, off);
        po += __shfl_down(po, off);
    }
    if (lane == 0) {
        srel[node] = pr;
        sroot[node] = po;
    }
}

// ---------------- K34: CSR + keys + SORTED-ROW front-chase fixpoint ----------------
// Order: earlier(u,v) <=> mono_u > mono_v || (mono_u==mono_v && u<v)  (== stable
// argsort(-score)). Keys are STATIC after phase 7; only status changes. So each
// row is filtered to earlier-in-nbrs and insertion-sorted by key ONCE; the
// fixpoint then chases the row front: absorber = first entry in key order that
// resolves center (provably == old mC<minU rule); absorbed entries are skipped
// exactly once; a blocked node polls ONE u8 status byte of its cached front.
// LDS: incsr u16 [0,128K). aux 32K: cursor i32 [0,16K) (ph 1-4) -> srel f64
// [0,32K) (ph 5-6) -> mono u32 [0,16K) + stat u8 [16K,20K) (ph 7+).
// wt ints @ aux+20544 (ph 2 scan, ph F scan).
__global__ void __launch_bounds__(1024) k34_contract(
        const double* __restrict__ srel, const double* __restrict__ sroot,
        const float* __restrict__ bptr, const int* __restrict__ ei,
        int* __restrict__ map_g, int* __restrict__ rem_g, int* __restrict__ relab_g,
        int* __restrict__ perm_a, int* __restrict__ nkeep_g) {
    __shared__ __align__(16) char buf[163840];
    unsigned short* incsr = (unsigned short*)buf;
    char* aux = buf + 131072;
    int* cursor = (int*)aux;
    double* srel_lds = (double*)aux;
    unsigned* mono_s = (unsigned*)aux;                                  // ph 7+
    volatile unsigned char* stat_s = (volatile unsigned char*)(aux + 16384);
    int* wt = (int*)(aux + 20544);
    int tid = threadIdx.x, lane = tid & 63, wv = tid >> 6;

    // ---- Phase 1: in-degree count (LDS atomics) ----
    for (int n = tid; n < NN; n += 1024) cursor[n] = 0;
    __syncthreads();
    const int4* eid4 = (const int4*)(ei + NE);
    for (int i = tid; i < NE / 4; i += 1024) {
        int4 q = eid4[i];
        atomicAdd(&cursor[q.x], 1);
        atomicAdd(&cursor[q.y], 1);
        atomicAdd(&cursor[q.z], 1);
        atomicAdd(&cursor[q.w], 1);
    }
    __syncthreads();

    // ---- Phase 2: exclusive prefix (wave scan); row starts in regs ----
    int t0 = cursor[4 * tid], t1 = cursor[4 * tid + 1];
    int t2 = cursor[4 * tid + 2], t3 = cursor[4 * tid + 3];
    int tot = t0 + t1 + t2 + t3;
    int inc = tot;
    for (int off = 1; off < 64; off <<= 1) {
        int v = __shfl_up(inc, off);
        if (lane >= off) inc += v;
    }
    if (lane == 63) wt[wv] = inc;
    __syncthreads();
    if (wv == 0 && lane < 16) {
        int v = wt[lane];
        for (int off = 1; off < 16; off <<= 1) {
            int u2 = __shfl_up(v, off);
            if (lane >= off) v += u2;
        }
        wt[lane] = v;
    }
    __syncthreads();
    int waveoff = (wv > 0) ? wt[wv - 1] : 0;
    int excl = waveoff + inc - tot;
    int rs4[4], re4[4];
    rs4[0] = excl; rs4[1] = excl + t0; rs4[2] = excl + t0 + t1; rs4[3] = excl + t0 + t1 + t2;
    cursor[4 * tid]     = rs4[0];
    cursor[4 * tid + 1] = rs4[1];
    cursor[4 * tid + 2] = rs4[2];
    cursor[4 * tid + 3] = rs4[3];
    __syncthreads();

    // ---- Phase 3: scatter in-edges (row = dst, entry = src node id) ----
    const int4* eis4 = (const int4*)ei;
    for (int i = tid; i < NE / 4; i += 1024) {
        int4 s = eis4[i];
        int4 d = eid4[i];
        incsr[atomicAdd(&cursor[d.x], 1)] = (unsigned short)s.x;
        incsr[atomicAdd(&cursor[d.y], 1)] = (unsigned short)s.y;
        incsr[atomicAdd(&cursor[d.z], 1)] = (unsigned short)s.z;
        incsr[atomicAdd(&cursor[d.w], 1)] = (unsigned short)s.w;
    }
    __syncthreads();
    #pragma unroll
    for (int t = 0; t < 4; ++t) re4[t] = cursor[4 * tid + t];   // row ends
    __syncthreads();   // cursor region now free

    // ---- Phase 5: stage srel into LDS (aliases cursor region) ----
    {
        double2* sl2 = (double2*)aux;
        const double2* sg2 = (const double2*)srel;
        for (int i = tid; i < NN / 2; i += 1024) sl2[i] = sg2[i];
    }
    __syncthreads();

    // ---- Phase 6: agg row-gather from LDS + monotone key computation (regs) ----
    double bv = (double)bptr[0];
    unsigned mono4[4];
    #pragma unroll
    for (int t = 0; t < 4; ++t) {
        int v = 4 * tid + t;
        double s = 0.0;
        for (int e = rs4[t]; e < re4[t]; ++e) s += srel_lds[(int)incsr[e]];
        double arg = s + sroot[v] + bv;
        float sc = tanhf((float)arg);                    // f32 saturation => ref ties
        unsigned m = __float_as_uint(sc);
        m = (m & 0x80000000u) ? ~m : (m | 0x80000000u);  // monotone ascending in score
        mono4[t] = m;
    }
    __syncthreads();   // all srel_lds reads done before mono/stat overwrite region

    // ---- Phase 7: publish static keys + zero status table ----
    #pragma unroll
    for (int t = 0; t < 4; ++t) mono_s[4 * tid + t] = mono4[t];
    ((int*)(aux + 16384))[tid] = 0;                      // 4096 stat bytes
    __syncthreads();

    // ---- Phase 8: filter rows to earlier-in-nbrs + insertion sort by key ----
    // sorted ascending by key  ==  descending mono, ties ascending id
    unsigned resolved = 0, centerm = 0, selfm = 0;
    int pos4[4], fu4[4] = {0, 0, 0, 0};
    #pragma unroll
    for (int t = 0; t < 4; ++t) {
        int v = 4 * tid + t;
        unsigned mv = mono4[t];
        int lo = rs4[t], w = lo;
        for (int e = lo; e < re4[t]; ++e) {
            int u = (int)incsr[e];
            if (u == v) { selfm |= 1u << t; continue; }
            unsigned mu = mono_s[u];
            if (!(mu > mv || (mu == mv && u < v))) continue;   // keep earlier only
            int j = w;
            while (j > lo) {
                int q = (int)incsr[j - 1];
                unsigned mq = mono_s[q];
                if (mu > mq || (mu == mq && u < q)) { incsr[j] = (unsigned short)q; --j; }
                else break;
            }
            incsr[j] = (unsigned short)u; ++w;
        }
        re4[t] = w; pos4[t] = lo;
        if (w == lo) {                                   // no earlier in-nbrs: center
            map_g[v] = v;
            stat_s[v] = 1;
            centerm |= 1u << t; resolved |= 1u << t;
        } else {
            fu4[t] = (int)incsr[lo];                     // cache row front
        }
    }

    // ---- Phase 8b: barrier-free front-chase fixpoint (u8 status polls) ----
    int guard = 0;
    while (resolved != 0xFu && guard < 1000000) {
        ++guard;
        bool prog = false;
        #pragma unroll
        for (int t = 0; t < 4; ++t) {
            if (resolved & (1u << t)) continue;
            int v = 4 * tid + t;
            int u = fu4[t];
            int st = (int)stat_s[u];
            if (st == 0) continue;                       // front unresolved: blocked
            prog = true;
            if (st == 1) {                               // front is center: absorbed
                map_g[v] = u; stat_s[v] = 2; resolved |= 1u << t; continue;
            }
            // st==2: front absorbed -> advance past absorbed entries
            int p = pos4[t] + 1, hi = re4[t];
            bool done = false;
            while (p < hi) {
                u = (int)incsr[p];
                st = (int)stat_s[u];
                if (st == 2) { ++p; continue; }
                if (st == 1) {
                    map_g[v] = u; stat_s[v] = 2; resolved |= 1u << t; done = true;
                }
                break;                                   // st==0: blocked here
            }
            if (!done) {
                if (p >= hi) {                           // all earlier absorbed: center
                    map_g[v] = v; stat_s[v] = 1; centerm |= 1u << t; resolved |= 1u << t;
                } else {
                    pos4[t] = p; fu4[t] = u;             // new blocked front
                }
            }
        }
        if (!prog) __builtin_amdgcn_s_sleep(1);
    }
    __syncthreads();

    // ---- Phase F: relabel prefix + perm + globals ----
    int remb[4], cnt4 = 0;
    #pragma unroll
    for (int t = 0; t < 4; ++t) {
        remb[t] = ((centerm >> t) & 1) && !((selfm >> t) & 1);
        cnt4 += remb[t];
    }
    int inc2 = cnt4;
    for (int off = 1; off < 64; off <<= 1) {
        int v = __shfl_up(inc2, off);
        if (lane >= off) inc2 += v;
    }
    if (lane == 63) wt[wv] = inc2;
    __syncthreads();
    if (wv == 0 && lane < 16) {
        int v = wt[lane];
        for (int off = 1; off < 16; off <<= 1) {
            int u2 = __shfl_up(v, off);
            if (lane >= off) v += u2;
        }
        wt[lane] = v;
    }
    __syncthreads();
    int woff2 = (wv > 0) ? wt[wv - 1] : 0;
    int run = woff2 + inc2 - cnt4;
    #pragma unroll
    for (int t = 0; t < 4; ++t) {
        int v = 4 * tid + t;
        relab_g[v] = run;
        if (remb[t]) { perm_a[run] = v; ++run; }
        rem_g[v] = remb[t];
    }
    if (tid == 1023) nkeep_g[0] = run;
}

// ---------------- K56: all outputs; x region is pure atomic-add over memset-0 --------
__global__ void k56_outputs(const float* __restrict__ x, const int* __restrict__ map_g,
                            const int* __restrict__ rem_g, const int* __restrict__ relab_g,
                            const int* __restrict__ perm_a, const int* __restrict__ ei,
                            const int* __restrict__ batch, const int* __restrict__ nkeep_g,
                            float* __restrict__ out) {
    int idx = blockIdx.x * blockDim.x + threadIdx.x;
    if (idx < NN * ND) {
        int n = idx >> 6, d = idx & 63;
        int m = map_g[n];                 // m==n for centers & kept free nodes
        if (rem_g[m]) atomicAdd(&out[relab_g[m] * ND + d], x[idx]);
    } else if (idx < NN * ND + 2 * NE) {
        int e = idx - NN * ND;
        int row = e >> 16;                // NE == 1<<16
        int ee = e & (NE - 1);
        int s = ei[ee], t = ei[NE + ee];
        bool valid = (rem_g[s] != 0) && (rem_g[t] != 0);
        int endp = (row == 0) ? s : t;
        out[idx] = valid ? (float)relab_g[endp] : -1.0f;
    } else if (idx < NN * ND + 2 * NE + NN) {
        int r = idx - (NN * ND + 2 * NE);
        int nk = nkeep_g[0];
        out[idx] = (r < nk) ? (float)batch[perm_a[r]] : -1.0f;
    } else if (idx < NN * ND + 2 * NE + 2 * NN) {
        int r = idx - (NN * ND + 2 * NE + NN);
        int nk = nkeep_g[0];
        out[idx] = (r < nk) ? (float)perm_a[r] : -1.0f;
    }
}

extern "C" void kernel_launch(void* const* d_in, const int* in_sizes, int n_in,
                              void* d_out, int out_size, void* d_ws, size_t ws_size,
                              hipStream_t stream) {
    const float* x     = (const float*)d_in[0];
    const int*   ei    = (const int*)d_in[1];
    const int*   batch = (const int*)d_in[2];
    const float* wrel  = (const float*)d_in[3];
    const float* wroot = (const float*)d_in[4];
    const float* b     = (const float*)d_in[5];

    char* ws = (char*)d_ws;
    double* srel  = (double*)(ws + 0);        // 32768
    double* sroot = (double*)(ws + 32768);    // 32768
    int*    map_g = (int*)(ws + 65536);       // 16384
    int*    rem_g = (int*)(ws + 81920);       // 16384
    int*    relab = (int*)(ws + 98304);       // 16384
    int*    perma = (int*)(ws + 114688);      // 16384
    int*    nkeep = (int*)(ws + 131072);      // 64

    float* out = (float*)d_out;

    hipMemsetAsync(out, 0, NN * ND * sizeof(float), stream);   // x_pooled base = 0
    k1_node_dots<<<NN * ND / 256, 256, 0, stream>>>(x, wrel, wroot, srel, sroot);
    k34_contract<<<1, 1024, 0, stream>>>(srel, sroot, b, ei, map_g, rem_g, relab,
                                         perma, nkeep);
    int total_out = NN * ND + 2 * NE + 2 * NN;  // 401408
    k56_outputs<<<(total_out + 255) / 256, 256, 0, stream>>>(x, map_g, rem_g, relab,
                                                             perma, ei, batch, nkeep, out);
}

// Round 3
// 162.160 us; speedup vs baseline: 2.5293x; 2.5293x over previous
//
#include <hip/hip_runtime.h>

#define NN 4096
#define NE 65536
#define ND 64

// ---------------- K1: per-node dot products (srel, sroot only) ----------------
__global__ void k1_node_dots(const float* __restrict__ x, const float* __restrict__ wrel,
                             const float* __restrict__ wroot, double* __restrict__ srel,
                             double* __restrict__ sroot) {
    int gt = blockIdx.x * blockDim.x + threadIdx.x;
    int node = gt >> 6, lane = gt & 63;
    if (node >= NN) return;
    double xv = (double)x[node * ND + lane];
    double pr = xv * (double)wrel[lane];
    double po = xv * (double)wroot[lane];
    for (int off = 32; off > 0; off >>= 1) {
        pr += __shfl_down(pr, off);
        po += __shfl_down(po, off);
    }
    if (lane == 0) {
        srel[node] = pr;
        sroot[node] = po;
    }
}

// ---------------- K34: CSR + keys + SORT-FREE barrier-free fixpoint ----------------
// Order comparisons use the key directly: earlier(u,v) <=> key_u < key_v where
// key = (~mono_f32_score)<<12 | node  (same order & ties as stable argsort(-score)).
// skey[node] u64 = (~mono)<<14 | node<<2 | stat packs order+status: ONE ds_read_b64
// per entry visit. stat updates only touch the low 2 bits => torn reads harmless.
// Sleep is BALLOT-GATED: a wave sleeps only if NO lane made progress this pass —
// the old per-lane `if (!prog) s_sleep` compiled to a scalar sleep taken under
// divergence whenever ANY lane stalled, putting 64-cy dead time on every pass of
// every wave, including waves hosting the critical dependency chain.
// LDS: incsr u16 [0,128K). aux 32K: cursor i32 [0,16K) (ph 1-4) -> srel f64 [0,32K)
// (ph 5-6) -> skey u64 [0,32K) (ph 7+). wt ints @ aux+20544 (ph 2 scan, ph F scan).
__global__ void __launch_bounds__(1024) k34_contract(
        const double* __restrict__ srel, const double* __restrict__ sroot,
        const float* __restrict__ bptr, const int* __restrict__ ei,
        int* __restrict__ map_g, int* __restrict__ rem_g, int* __restrict__ relab_g,
        int* __restrict__ perm_a, int* __restrict__ nkeep_g) {
    __shared__ __align__(16) char buf[163840];
    unsigned short* incsr = (unsigned short*)buf;
    char* aux = buf + 131072;
    int* cursor = (int*)aux;
    double* srel_lds = (double*)aux;
    volatile unsigned long long* skey = (volatile unsigned long long*)aux;
    int* wt = (int*)(aux + 20544);
    int tid = threadIdx.x, lane = tid & 63, wv = tid >> 6;

    // ---- Phase 1: in-degree count (LDS atomics) ----
    for (int n = tid; n < NN; n += 1024) cursor[n] = 0;
    __syncthreads();
    const int4* eid4 = (const int4*)(ei + NE);
    for (int i = tid; i < NE / 4; i += 1024) {
        int4 q = eid4[i];
        atomicAdd(&cursor[q.x], 1);
        atomicAdd(&cursor[q.y], 1);
        atomicAdd(&cursor[q.z], 1);
        atomicAdd(&cursor[q.w], 1);
    }
    __syncthreads();

    // ---- Phase 2: exclusive prefix (wave scan); row starts in regs ----
    int t0 = cursor[4 * tid], t1 = cursor[4 * tid + 1];
    int t2 = cursor[4 * tid + 2], t3 = cursor[4 * tid + 3];
    int tot = t0 + t1 + t2 + t3;
    int inc = tot;
    for (int off = 1; off < 64; off <<= 1) {
        int v = __shfl_up(inc, off);
        if (lane >= off) inc += v;
    }
    if (lane == 63) wt[wv] = inc;
    __syncthreads();
    if (wv == 0 && lane < 16) {
        int v = wt[lane];
        for (int off = 1; off < 16; off <<= 1) {
            int u2 = __shfl_up(v, off);
            if (lane >= off) v += u2;
        }
        wt[lane] = v;
    }
    __syncthreads();
    int waveoff = (wv > 0) ? wt[wv - 1] : 0;
    int excl = waveoff + inc - tot;
    int rs4[4], re4[4];
    rs4[0] = excl; rs4[1] = excl + t0; rs4[2] = excl + t0 + t1; rs4[3] = excl + t0 + t1 + t2;
    cursor[4 * tid]     = rs4[0];
    cursor[4 * tid + 1] = rs4[1];
    cursor[4 * tid + 2] = rs4[2];
    cursor[4 * tid + 3] = rs4[3];
    __syncthreads();

    // ---- Phase 3: scatter in-edges (row = dst, entry = src node id) ----
    const int4* eis4 = (const int4*)ei;
    for (int i = tid; i < NE / 4; i += 1024) {
        int4 s = eis4[i];
        int4 d = eid4[i];
        incsr[atomicAdd(&cursor[d.x], 1)] = (unsigned short)s.x;
        incsr[atomicAdd(&cursor[d.y], 1)] = (unsigned short)s.y;
        incsr[atomicAdd(&cursor[d.z], 1)] = (unsigned short)s.z;
        incsr[atomicAdd(&cursor[d.w], 1)] = (unsigned short)s.w;
    }
    __syncthreads();
    for (int t = 0; t < 4; ++t) re4[t] = cursor[4 * tid + t];   // row ends
    __syncthreads();   // cursor region now free

    // ---- Phase 5: stage srel into LDS (aliases cursor region) ----
    {
        double2* sl2 = (double2*)aux;
        const double2* sg2 = (const double2*)srel;
        for (int i = tid; i < NN / 2; i += 1024) sl2[i] = sg2[i];
    }
    __syncthreads();

    // ---- Phase 6: agg row-gather from LDS + key/base computation (regs only) ----
    double bv = (double)bptr[0];
    unsigned long long base4[4];
    for (int t = 0; t < 4; ++t) {
        int v = 4 * tid + t;
        double s = 0.0;
        for (int e = rs4[t]; e < re4[t]; ++e) s += srel_lds[(int)incsr[e]];
        double arg = s + sroot[v] + bv;
        float sc = tanhf((float)arg);                    // f32 saturation => ref ties
        unsigned m = __float_as_uint(sc);
        m = (m & 0x80000000u) ? ~m : (m | 0x80000000u);  // monotone ascending
        base4[t] = ((unsigned long long)(~m) << 14) | ((unsigned long long)v << 2);
    }
    __syncthreads();   // all srel_lds reads done before skey overwrites the region

    // ---- Phase 7: init skey table ----
    for (int t = 0; t < 4; ++t) skey[4 * tid + t] = base4[t];
    __syncthreads();

    // ---- Phase 8, round 0: filter rows (keep earlier in-nbrs only, note self) ----
    unsigned long long pk4[4], minC4[4];
    unsigned resolved = 0, centerm = 0, selfm = 0;
    for (int t = 0; t < 4; ++t) {
        int v = 4 * tid + t;
        unsigned long long pkv = base4[t] >> 2;
        pk4[t] = pkv;
        minC4[t] = ~0ULL;
        int w = rs4[t];
        for (int e = rs4[t]; e < re4[t]; ++e) {
            int u = (int)incsr[e];
            if (u == v) { selfm |= 1u << t; continue; }
            unsigned long long ku = skey[u] >> 2;        // stat bits shifted out
            if (ku < pkv) incsr[w++] = (unsigned short)u;
        }
        re4[t] = w;
        if (w == rs4[t]) {                               // no earlier in-nbrs: center
            map_g[v] = v;
            skey[v] = base4[t] | 1ULL;
            centerm |= 1u << t; resolved |= 1u << t;
        }
    }

    // ---- Phase 8b: barrier-free monotone dataflow fixpoint ----
    int guard = 0;
    while (resolved != 0xFu && guard < 1000000) {
        ++guard;
        bool prog = false;
        for (int t = 0; t < 4; ++t) {
            if (resolved & (1u << t)) continue;
            int v = 4 * tid + t;
            int lo = rs4[t], hi = re4[t];
            unsigned long long minU = ~0ULL, mC = minC4[t];
            int w = lo;
            for (int e = lo; e < hi; ++e) {
                int u = (int)incsr[e];
                unsigned long long sk = skey[u];
                int st = (int)(sk & 3ULL);
                unsigned long long ku = sk >> 2;
                if (st == 0) { incsr[w++] = (unsigned short)u; if (ku < minU) minU = ku; }
                else if (st == 1) { if (ku < mC) mC = ku; }
                // st==2: absorbed, drop
            }
            if (w != hi) prog = true;
            re4[t] = w; minC4[t] = mC;
            if (mC < minU) {                             // first absorber known
                map_g[v] = (int)((mC >> 2) & 0xFFFULL);  // decode node id
                skey[v] = (pk4[t] << 2) | 2ULL;
                resolved |= 1u << t; prog = true;
            } else if (w == lo) {                        // all earlier resolved non-center
                map_g[v] = v;
                skey[v] = (pk4[t] << 2) | 1ULL;
                centerm |= 1u << t; resolved |= 1u << t; prog = true;
            }
        }
        if (__ballot(prog) == 0) __builtin_amdgcn_s_sleep(1);  // wave-wide idle only
    }
    __syncthreads();

    // ---- Phase F: relabel prefix + perm + globals ----
    int remb[4], cnt4 = 0;
    for (int t = 0; t < 4; ++t) {
        remb[t] = ((centerm >> t) & 1) && !((selfm >> t) & 1);
        cnt4 += remb[t];
    }
    int inc2 = cnt4;
    for (int off = 1; off < 64; off <<= 1) {
        int v = __shfl_up(inc2, off);
        if (lane >= off) inc2 += v;
    }
    if (lane == 63) wt[wv] = inc2;
    __syncthreads();
    if (wv == 0 && lane < 16) {
        int v = wt[lane];
        for (int off = 1; off < 16; off <<= 1) {
            int u2 = __shfl_up(v, off);
            if (lane >= off) v += u2;
        }
        wt[lane] = v;
    }
    __syncthreads();
    int woff2 = (wv > 0) ? wt[wv - 1] : 0;
    int run = woff2 + inc2 - cnt4;
    for (int t = 0; t < 4; ++t) {
        int v = 4 * tid + t;
        relab_g[v] = run;
        if (remb[t]) { perm_a[run] = v; ++run; }
        rem_g[v] = remb[t];
    }
    if (tid == 1023) nkeep_g[0] = run;
}

// ---------------- K56: all outputs; x region is pure atomic-add over memset-0 --------
__global__ void k56_outputs(const float* __restrict__ x, const int* __restrict__ map_g,
                            const int* __restrict__ rem_g, const int* __restrict__ relab_g,
                            const int* __restrict__ perm_a, const int* __restrict__ ei,
                            const int* __restrict__ batch, const int* __restrict__ nkeep_g,
                            float* __restrict__ out) {
    int idx = blockIdx.x * blockDim.x + threadIdx.x;
    if (idx < NN * ND) {
        int n = idx >> 6, d = idx & 63;
        int m = map_g[n];                 // m==n for centers & kept free nodes
        if (rem_g[m]) atomicAdd(&out[relab_g[m] * ND + d], x[idx]);
    } else if (idx < NN * ND + 2 * NE) {
        int e = idx - NN * ND;
        int row = e >> 16;                // NE == 1<<16
        int ee = e & (NE - 1);
        int s = ei[ee], t = ei[NE + ee];
        bool valid = (rem_g[s] != 0) && (rem_g[t] != 0);
        int endp = (row == 0) ? s : t;
        out[idx] = valid ? (float)relab_g[endp] : -1.0f;
    } else if (idx < NN * ND + 2 * NE + NN) {
        int r = idx - (NN * ND + 2 * NE);
        int nk = nkeep_g[0];
        out[idx] = (r < nk) ? (float)batch[perm_a[r]] : -1.0f;
    } else if (idx < NN * ND + 2 * NE + 2 * NN) {
        int r = idx - (NN * ND + 2 * NE + NN);
        int nk = nkeep_g[0];
        out[idx] = (r < nk) ? (float)perm_a[r] : -1.0f;
    }
}

extern "C" void kernel_launch(void* const* d_in, const int* in_sizes, int n_in,
                              void* d_out, int out_size, void* d_ws, size_t ws_size,
                              hipStream_t stream) {
    const float* x     = (const float*)d_in[0];
    const int*   ei    = (const int*)d_in[1];
    const int*   batch = (const int*)d_in[2];
    const float* wrel  = (const float*)d_in[3];
    const float* wroot = (const float*)d_in[4];
    const float* b     = (const float*)d_in[5];

    char* ws = (char*)d_ws;
    double* srel  = (double*)(ws + 0);        // 32768
    double* sroot = (double*)(ws + 32768);    // 32768
    int*    map_g = (int*)(ws + 65536);       // 16384
    int*    rem_g = (int*)(ws + 81920);       // 16384
    int*    relab = (int*)(ws + 98304);       // 16384
    int*    perma = (int*)(ws + 114688);      // 16384
    int*    nkeep = (int*)(ws + 131072);      // 64

    float* out = (float*)d_out;

    hipMemsetAsync(out, 0, NN * ND * sizeof(float), stream);   // x_pooled base = 0
    k1_node_dots<<<NN * ND / 256, 256, 0, stream>>>(x, wrel, wroot, srel, sroot);
    k34_contract<<<1, 1024, 0, stream>>>(srel, sroot, b, ei, map_g, rem_g, relab,
                                         perma, nkeep);
    int total_out = NN * ND + 2 * NE + 2 * NN;  // 401408
    k56_outputs<<<(total_out + 255) / 256, 256, 0, stream>>>(x, map_g, rem_g, relab,
                                                             perma, ei, batch, nkeep, out);
}

// Round 4
// 141.979 us; speedup vs baseline: 2.8888x; 1.1421x over previous
//
#include <hip/hip_runtime.h>

#define NN 4096
#define NE 65536
#define ND 64

// ---------- workspace layout (bytes) ----------
// 0      : srel   f64[NN]   (32768)
// 32768  : sroot  f64[NN]   (32768)
// 65536  : map    i32[NN]
// 81920  : rem    i32[NN]
// 98304  : relab  i32[NN]
// 114688 : perma  i32[NN]
// 131072 : nkeep  i32
// 131136 : cnt    i32[NN]   (K1)  -> rl (len|self<<16) i32[NN] (K5+)
// 147520 : rowst  i32[NN+1] (pad to 16448)
// 163968 : cursor i32[NN]   (K3)  -> key u32[NN] (K4+)
// 180352 : incsr  u16[NE]   (128K; K3 scatter, K5 sorts in place)
// total  : 311424 bytes

// ---------------- K1: per-node dots + in-degree count (multi-CU) ----------------
__global__ void k1_dots_count(const float* __restrict__ x, const float* __restrict__ wrel,
                              const float* __restrict__ wroot, const int* __restrict__ ei,
                              double* __restrict__ srel, double* __restrict__ sroot,
                              int* __restrict__ cnt) {
    int gt = blockIdx.x * blockDim.x + threadIdx.x;
    int node = gt >> 6, lane = gt & 63;
    double xv = (double)x[node * ND + lane];
    double pr = xv * (double)wrel[lane];
    double po = xv * (double)wroot[lane];
    for (int off = 32; off > 0; off >>= 1) {
        pr += __shfl_down(pr, off);
        po += __shfl_down(po, off);
    }
    if (lane == 0) {
        srel[node] = pr;
        sroot[node] = po;
    }
    if (gt < NE / 4) {                                   // extra role: degree count
        const int4* eid4 = (const int4*)(ei + NE);
        int4 q = eid4[gt];
        atomicAdd(&cnt[q.x], 1);
        atomicAdd(&cnt[q.y], 1);
        atomicAdd(&cnt[q.z], 1);
        atomicAdd(&cnt[q.w], 1);
    }
}

// ---------------- K2: exclusive prefix scan of degrees (1 block) ----------------
__global__ void __launch_bounds__(1024) k2_scan(const int* __restrict__ cnt,
                                                int* __restrict__ rowst,
                                                int* __restrict__ cursor) {
    __shared__ int wt[16];
    int tid = threadIdx.x, lane = tid & 63, wv = tid >> 6;
    int4 c = ((const int4*)cnt)[tid];
    int tot = c.x + c.y + c.z + c.w;
    int inc = tot;
    for (int off = 1; off < 64; off <<= 1) {
        int v = __shfl_up(inc, off);
        if (lane >= off) inc += v;
    }
    if (lane == 63) wt[wv] = inc;
    __syncthreads();
    if (wv == 0 && lane < 16) {
        int v = wt[lane];
        for (int off = 1; off < 16; off <<= 1) {
            int u2 = __shfl_up(v, off);
            if (lane >= off) v += u2;
        }
        wt[lane] = v;
    }
    __syncthreads();
    int waveoff = (wv > 0) ? wt[wv - 1] : 0;
    int excl = waveoff + inc - tot;
    int4 rs;
    rs.x = excl; rs.y = excl + c.x; rs.z = excl + c.x + c.y; rs.w = excl + c.x + c.y + c.z;
    ((int4*)rowst)[tid] = rs;
    ((int4*)cursor)[tid] = rs;
    if (tid == 0) rowst[NN] = NE;
}

// ---------------- K3: scatter in-edges (row = dst, entry = src) ----------------
__global__ void k3_scatter(const int* __restrict__ ei, int* __restrict__ cursor,
                           unsigned short* __restrict__ incsr) {
    int i = blockIdx.x * blockDim.x + threadIdx.x;     // i < NE/4
    const int4* eis4 = (const int4*)ei;
    const int4* eid4 = (const int4*)(ei + NE);
    int4 s = eis4[i];
    int4 d = eid4[i];
    incsr[atomicAdd(&cursor[d.x], 1)] = (unsigned short)s.x;
    incsr[atomicAdd(&cursor[d.y], 1)] = (unsigned short)s.y;
    incsr[atomicAdd(&cursor[d.z], 1)] = (unsigned short)s.z;
    incsr[atomicAdd(&cursor[d.w], 1)] = (unsigned short)s.w;
}

// ---------------- K4: per-node agg + monotone key (multi-CU) ----------------
__global__ void k4_keys(const double* __restrict__ srel, const double* __restrict__ sroot,
                        const float* __restrict__ bptr, const int* __restrict__ rowst,
                        const unsigned short* __restrict__ incsr, unsigned* __restrict__ key) {
    int v = blockIdx.x * blockDim.x + threadIdx.x;     // v < NN
    int rs = rowst[v], re = rowst[v + 1];
    double s = 0.0;
    for (int e = rs; e < re; ++e) s += srel[(int)incsr[e]];
    double arg = s + sroot[v] + (double)bptr[0];
    float sc = tanhf((float)arg);                      // f32 saturation => ref ties
    unsigned m = __float_as_uint(sc);
    m = (m & 0x80000000u) ? ~m : (m | 0x80000000u);    // monotone ascending in score
    key[v] = m;
}

// ---------------- K5: per-row filter (earlier-only) + 64-lane bitonic sort ----------
// One wave per row. earlier(u,v) <=> key_u>key_v || (key_u==key_v && u<v); sortval
// ascending = ((~key_u)<<12 | u) puts earliest first. Rows sorted in place.
__global__ void k5_filtersort(const int* __restrict__ rowst, const unsigned* __restrict__ key,
                              unsigned short* __restrict__ incsr, int* __restrict__ rl) {
    int gt = blockIdx.x * blockDim.x + threadIdx.x;
    int v = gt >> 6, l = gt & 63;
    int rs = rowst[v], deg = rowst[v + 1] - rs;
    unsigned mv = key[v];
    if (deg <= 64) {
        int u = (l < deg) ? (int)incsr[rs + l] : -1;
        bool isself = (l < deg) && (u == v);
        unsigned mu = (l < deg && !isself) ? key[u] : 0u;
        bool keep = (l < deg) && !isself && (mu > mv || (mu == mv && u < v));
        unsigned long long val = keep
            ? ((((unsigned long long)(~mu)) << 12) | (unsigned)u) : ~0ULL;
        int m = __popcll(__ballot(keep));
        bool selfAny = __ballot(isself) != 0ULL;
        // bitonic ascending over 64 lanes
        for (int k = 2; k <= 64; k <<= 1) {
            for (int j = k >> 1; j > 0; j >>= 1) {
                unsigned long long o = __shfl_xor(val, j);
                bool takeMin = ((l & k) == 0) == ((l & j) == 0);
                unsigned long long mn = (o < val) ? o : val;
                unsigned long long mx = (o < val) ? val : o;
                val = takeMin ? mn : mx;
            }
        }
        if (l < m) incsr[rs + l] = (unsigned short)(val & 0xFFFULL);
        if (l == 0) rl[v] = m | (selfAny ? 0x10000 : 0);
    } else if (l == 0) {
        // fallback (not expected for this input): sequential in-place filter+insert
        int w = rs;
        bool selfAny = false;
        for (int e = rs; e < rs + deg; ++e) {
            int u = (int)incsr[e];
            if (u == v) { selfAny = true; continue; }
            unsigned mu = key[u];
            if (!(mu > mv || (mu == mv && u < v))) continue;
            int j = w;
            while (j > rs) {
                int q = (int)incsr[j - 1];
                unsigned mq = key[q];
                if (mu > mq || (mu == mq && u < q)) { incsr[j] = (unsigned short)q; --j; }
                else break;
            }
            incsr[j] = (unsigned short)u; ++w;
        }
        rl[v] = (w - rs) | (selfAny ? 0x10000 : 0);
    }
}

// ---------------- K34: 1-CU front-chase fixpoint on pre-sorted rows ----------------
// Sorted rows make the r2-verified front-chase sort-free: front = min live key;
// front center => absorb by it (== mC<minU); front unresolved => blocked; absorbed
// fronts skipped exactly once; exhausted => center. Polls are 1 u8 LDS read.
__global__ void __launch_bounds__(1024) k34_fix(
        const int* __restrict__ rowst, const int* __restrict__ rl,
        const unsigned short* __restrict__ incsr_g,
        int* __restrict__ map_g, int* __restrict__ rem_g, int* __restrict__ relab_g,
        int* __restrict__ perm_a, int* __restrict__ nkeep_g) {
    __shared__ __align__(16) char buf[135232];
    unsigned short* incsr = (unsigned short*)buf;                       // 128K
    volatile unsigned char* stat = (volatile unsigned char*)(buf + 131072);  // 4K
    int* wt = (int*)(buf + 135168);
    int tid = threadIdx.x, lane = tid & 63, wv = tid >> 6;

    // load sorted CSR into LDS + zero status
    for (int i = tid; i < 131072 / 16; i += 1024)
        ((int4*)incsr)[i] = ((const int4*)incsr_g)[i];
    ((int*)(buf + 131072))[tid] = 0;
    int4 rsq = ((const int4*)rowst)[tid];
    int4 rlq = ((const int4*)rl)[tid];
    int rs4[4] = {rsq.x, rsq.y, rsq.z, rsq.w};
    int rq4[4] = {rlq.x, rlq.y, rlq.z, rlq.w};
    __syncthreads();

    unsigned resolved = 0, centerm = 0, selfm = 0;
    int pos4[4], re4[4], fu4[4] = {0, 0, 0, 0};
    #pragma unroll
    for (int t = 0; t < 4; ++t) {
        int v = 4 * tid + t;
        int m = rq4[t] & 0xFFFF;
        if (rq4[t] & 0x10000) selfm |= 1u << t;
        int lo = rs4[t];
        pos4[t] = lo; re4[t] = lo + m;
        if (m == 0) {                                    // no earlier in-nbrs: center
            map_g[v] = v; stat[v] = 1;
            centerm |= 1u << t; resolved |= 1u << t;
        } else {
            fu4[t] = (int)incsr[lo];
        }
    }

    int guard = 0;
    while (resolved != 0xFu && guard < 1000000) {
        ++guard;
        bool prog = false;
        #pragma unroll
        for (int t = 0; t < 4; ++t) {
            if (resolved & (1u << t)) continue;
            int v = 4 * tid + t;
            int u = fu4[t];
            int st = (int)stat[u];
            if (st == 0) continue;                       // front unresolved: blocked
            prog = true;
            if (st == 1) {                               // front is center: absorbed
                map_g[v] = u; stat[v] = 2; resolved |= 1u << t; continue;
            }
            int p = pos4[t] + 1, hi = re4[t];            // front absorbed: advance
            bool done = false;
            while (p < hi) {
                u = (int)incsr[p];
                st = (int)stat[u];
                if (st == 2) { ++p; continue; }
                if (st == 1) {
                    map_g[v] = u; stat[v] = 2; resolved |= 1u << t; done = true;
                }
                break;                                   // st==0: blocked here
            }
            if (!done) {
                if (p >= hi) {                           // all earlier absorbed: center
                    map_g[v] = v; stat[v] = 1; centerm |= 1u << t; resolved |= 1u << t;
                } else {
                    pos4[t] = p; fu4[t] = u;
                }
            }
        }
        if (__ballot(prog) == 0) __builtin_amdgcn_s_sleep(1);
    }
    __syncthreads();

    // relabel prefix + perm + globals
    int remb[4], cnt4 = 0;
    #pragma unroll
    for (int t = 0; t < 4; ++t) {
        remb[t] = ((centerm >> t) & 1) && !((selfm >> t) & 1);
        cnt4 += remb[t];
    }
    int inc2 = cnt4;
    for (int off = 1; off < 64; off <<= 1) {
        int v = __shfl_up(inc2, off);
        if (lane >= off) inc2 += v;
    }
    if (lane == 63) wt[wv] = inc2;
    __syncthreads();
    if (wv == 0 && lane < 16) {
        int v = wt[lane];
        for (int off = 1; off < 16; off <<= 1) {
            int u2 = __shfl_up(v, off);
            if (lane >= off) v += u2;
        }
        wt[lane] = v;
    }
    __syncthreads();
    int woff2 = (wv > 0) ? wt[wv - 1] : 0;
    int run = woff2 + inc2 - cnt4;
    #pragma unroll
    for (int t = 0; t < 4; ++t) {
        int v = 4 * tid + t;
        relab_g[v] = run;
        if (remb[t]) { perm_a[run] = v; ++run; }
        rem_g[v] = remb[t];
    }
    if (tid == 1023) nkeep_g[0] = run;
}

// ---------------- K56: all outputs; x region is pure atomic-add over memset-0 --------
__global__ void k56_outputs(const float* __restrict__ x, const int* __restrict__ map_g,
                            const int* __restrict__ rem_g, const int* __restrict__ relab_g,
                            const int* __restrict__ perm_a, const int* __restrict__ ei,
                            const int* __restrict__ batch, const int* __restrict__ nkeep_g,
                            float* __restrict__ out) {
    int idx = blockIdx.x * blockDim.x + threadIdx.x;
    if (idx < NN * ND) {
        int n = idx >> 6, d = idx & 63;
        int m = map_g[n];                 // m==n for centers & kept free nodes
        if (rem_g[m]) atomicAdd(&out[relab_g[m] * ND + d], x[idx]);
    } else if (idx < NN * ND + 2 * NE) {
        int e = idx - NN * ND;
        int row = e >> 16;                // NE == 1<<16
        int ee = e & (NE - 1);
        int s = ei[ee], t = ei[NE + ee];
        bool valid = (rem_g[s] != 0) && (rem_g[t] != 0);
        int endp = (row == 0) ? s : t;
        out[idx] = valid ? (float)relab_g[endp] : -1.0f;
    } else if (idx < NN * ND + 2 * NE + NN) {
        int r = idx - (NN * ND + 2 * NE);
        int nk = nkeep_g[0];
        out[idx] = (r < nk) ? (float)batch[perm_a[r]] : -1.0f;
    } else if (idx < NN * ND + 2 * NE + 2 * NN) {
        int r = idx - (NN * ND + 2 * NE + NN);
        int nk = nkeep_g[0];
        out[idx] = (r < nk) ? (float)perm_a[r] : -1.0f;
    }
}

extern "C" void kernel_launch(void* const* d_in, const int* in_sizes, int n_in,
                              void* d_out, int out_size, void* d_ws, size_t ws_size,
                              hipStream_t stream) {
    const float* x     = (const float*)d_in[0];
    const int*   ei    = (const int*)d_in[1];
    const int*   batch = (const int*)d_in[2];
    const float* wrel  = (const float*)d_in[3];
    const float* wroot = (const float*)d_in[4];
    const float* b     = (const float*)d_in[5];

    char* ws = (char*)d_ws;
    double* srel   = (double*)(ws + 0);
    double* sroot  = (double*)(ws + 32768);
    int*    map_g  = (int*)(ws + 65536);
    int*    rem_g  = (int*)(ws + 81920);
    int*    relab  = (int*)(ws + 98304);
    int*    perma  = (int*)(ws + 114688);
    int*    nkeep  = (int*)(ws + 131072);
    int*    cnt    = (int*)(ws + 131136);      // -> rl after K5
    int*    rowst  = (int*)(ws + 147520);
    int*    cursor = (int*)(ws + 163968);      // -> key after K4
    unsigned short* incsr = (unsigned short*)(ws + 180352);
    int*      rl  = cnt;
    unsigned* key = (unsigned*)cursor;

    float* out = (float*)d_out;

    hipMemsetAsync(out, 0, NN * ND * sizeof(float), stream);   // x_pooled base = 0
    hipMemsetAsync(cnt, 0, NN * sizeof(int), stream);
    k1_dots_count<<<NN * ND / 256, 256, 0, stream>>>(x, wrel, wroot, ei, srel, sroot, cnt);
    k2_scan<<<1, 1024, 0, stream>>>(cnt, rowst, cursor);
    k3_scatter<<<(NE / 4) / 256, 256, 0, stream>>>(ei, cursor, incsr);
    k4_keys<<<NN / 256, 256, 0, stream>>>(srel, sroot, b, rowst, incsr, key);
    k5_filtersort<<<(NN * 64) / 256, 256, 0, stream>>>(rowst, key, incsr, rl);
    k34_fix<<<1, 1024, 0, stream>>>(rowst, rl, incsr, map_g, rem_g, relab, perma, nkeep);
    int total_out = NN * ND + 2 * NE + 2 * NN;  // 401408
    k56_outputs<<<(total_out + 255) / 256, 256, 0, stream>>>(x, map_g, rem_g, relab,
                                                             perma, ei, batch, nkeep, out);
}